// Round 3
// baseline (306.920 us; speedup 1.0000x reference)
//
#include <hip/hip_runtime.h>
#include <stdint.h>
#include <stddef.h>

// gcnmask: N=50000 nodes, DEG=16, F=128. Edges grouped by dst (dst = e/16) -> no atomics.
// R3: 4-node blocks, acc[2][2] (16 AGPR) for 6 waves/SIMD; B-fragments from global (L1);
//     LDS only 8.4 KB (xn); final_agg vectorized ushort4 gathers.

#define NNODES 50000
#define DEG    16
#define FD     128
#define K2     256   // 2*F

typedef __bf16 bf16x8 __attribute__((ext_vector_type(8)));
typedef short  s16x8  __attribute__((ext_vector_type(8)));
typedef float  f32x4  __attribute__((ext_vector_type(4)));

__device__ __forceinline__ short f2bf_s(float f) {
    union { float f; uint32_t u; } v; v.f = f;
    uint32_t r = v.u + 0x7fffu + ((v.u >> 16) & 1u);   // RNE
    return (short)(r >> 16);
}
__device__ __forceinline__ float bf2f(short s) {
    union { uint32_t u; float f; } v; v.u = ((uint32_t)(uint16_t)s) << 16;
    return v.f;
}

// Pack weights_mask [256x128] and weight [128x128] into bf16 B-fragment order for
// mfma_f32_16x16x32_bf16: idx = ((kk*8+nt)*64 + q*16 + n15)*8 + (k&7).
// Also convert x [50000x128] fp32 -> bf16 row-major (8 elems/thread).
__global__ __launch_bounds__(256) void pack_k(const float* __restrict__ x,
                                              const float* __restrict__ wm,
                                              const float* __restrict__ w,
                                              short* __restrict__ bpack,
                                              short* __restrict__ wpack,
                                              short* __restrict__ xbf) {
    int tid = blockIdx.x * 256 + threadIdx.x;      // 3125*256 = 800000 = (50000*128)/8
    {
        const f32x4* s = reinterpret_cast<const f32x4*>(x) + (size_t)tid * 2;
        f32x4 a = s[0], b = s[1];
        s16x8 o;
        o[0]=f2bf_s(a.x); o[1]=f2bf_s(a.y); o[2]=f2bf_s(a.z); o[3]=f2bf_s(a.w);
        o[4]=f2bf_s(b.x); o[5]=f2bf_s(b.y); o[6]=f2bf_s(b.z); o[7]=f2bf_s(b.w);
        reinterpret_cast<s16x8*>(xbf)[tid] = o;
    }
    if (tid < K2 * FD) {
        int k = tid >> 7, n = tid & 127;
        int idx = (((k >> 5) * 8 + (n >> 4)) * 64 + ((k >> 3) & 3) * 16 + (n & 15)) * 8 + (k & 7);
        bpack[idx] = f2bf_s(wm[tid]);
    }
    if (tid < FD * FD) {
        int k = tid >> 7, n = tid & 127;
        int idx = (((k >> 5) * 8 + (n >> 4)) * 64 + ((k >> 3) & 3) * 16 + (n & 15)) * 8 + (k & 7);
        wpack[idx] = f2bf_s(w[tid]);
    }
}

// Block = 512 threads = 8 waves, 4 nodes. wave = wh*2 + wp:
//   wp = wave&1 -> node pair (2 Mtiles), wh = wave>>1 (0..3) -> 2 Ntiles (32 features).
// Phase 1: mask GEMM, acc[2][2] (16 AGPR); A gathered bf16 16B/lane; B (Wm packed) from global.
// Phase 2: sigmoid + agg quad-shuffle-reduce -> xn[16 x 132] LDS (rows 4..15 zeroed).
// Phase 3: support[4 x 128] = xn @ weight, wave w -> Ntile w, one Mtile (rows 4..15 discarded).
__global__ __launch_bounds__(512, 6) void mask_agg_support_k(
    const float* __restrict__ x, const short* __restrict__ xbf,
    const int* __restrict__ esrc,
    const short* __restrict__ bpack, const short* __restrict__ wpack,
    short* __restrict__ support)
{
    __shared__ float xn[16 * 132];   // 8.4 KB; stride 132 avoids bank conflicts on phase-3 reads

    const int tid   = threadIdx.x;
    const int wave  = tid >> 6;
    const int lane  = tid & 63;
    const int q     = lane >> 4;
    const int m     = lane & 15;
    const int wp    = wave & 1;                     // node pair
    const int wh    = wave >> 1;                    // feature quarter (2 ntiles)
    const int node0 = blockIdx.x * 4;
    const int wn0   = node0 + wp * 2;

    // zero xn (rows 4..15 feed garbage-free into phase-3 MFMA); 2112 floats / 512 threads
    #pragma unroll
    for (int i = tid; i < 16 * 132; i += 512) xn[i] = 0.f;

    int srcid[2];
    #pragma unroll
    for (int mt = 0; mt < 2; ++mt) srcid[mt] = esrc[(wn0 + mt) * DEG + m];

    f32x4 acc[2][2];
    #pragma unroll
    for (int mt = 0; mt < 2; ++mt)
        #pragma unroll
        for (int nt = 0; nt < 2; ++nt)
            acc[mt][nt] = (f32x4){0.f, 0.f, 0.f, 0.f};

    #pragma unroll
    for (int kk = 0; kk < 8; ++kk) {
        bf16x8 af[2];
        #pragma unroll
        for (int mt = 0; mt < 2; ++mt) {
            // A layout: row = m (edge), k = kk*32 + q*8 + j. kk<4: center row (uniform); kk>=4: neighbor.
            const int row = (kk < 4) ? (wn0 + mt) : srcid[mt];
            const short* rp = xbf + (size_t)row * FD + ((kk & 3) * 32 + q * 8);
            af[mt] = __builtin_bit_cast(bf16x8, *reinterpret_cast<const s16x8*>(rp));
        }
        #pragma unroll
        for (int nt = 0; nt < 2; ++nt) {
            const int ntile = wh * 2 + nt;
            s16x8 braw = *reinterpret_cast<const s16x8*>(bpack + ((size_t)(kk * 8 + ntile) * 64 + lane) * 8);
            bf16x8 bfr = __builtin_bit_cast(bf16x8, braw);
            #pragma unroll
            for (int mt = 0; mt < 2; ++mt)
                acc[mt][nt] = __builtin_amdgcn_mfma_f32_16x16x32_bf16(af[mt], bfr, acc[mt][nt], 0, 0, 0);
        }
    }

    // Phase 2: C/D layout: col = lane&15 (feature), row = q*4 + i (edge within node)
    #pragma unroll
    for (int mt = 0; mt < 2; ++mt) {
        const int node = wn0 + mt;
        const int s0 = __shfl(srcid[mt], q * 4 + 0);
        const int s1 = __shfl(srcid[mt], q * 4 + 1);
        const int s2 = __shfl(srcid[mt], q * 4 + 2);
        const int s3 = __shfl(srcid[mt], q * 4 + 3);
        #pragma unroll
        for (int nt = 0; nt < 2; ++nt) {
            const int f = (wh * 2 + nt) * 16 + m;
            f32x4 z = acc[mt][nt];
            float g0 = 1.f / (1.f + __expf(-z.x));
            float g1 = 1.f / (1.f + __expf(-z.y));
            float g2 = 1.f / (1.f + __expf(-z.z));
            float g3 = 1.f / (1.f + __expf(-z.w));
            float p = g0 * bf2f(xbf[(size_t)s0 * FD + f])
                    + g1 * bf2f(xbf[(size_t)s1 * FD + f])
                    + g2 * bf2f(xbf[(size_t)s2 * FD + f])
                    + g3 * bf2f(xbf[(size_t)s3 * FD + f]);
            p += __shfl_xor(p, 16);
            p += __shfl_xor(p, 32);
            if (q == 0) xn[(wp * 2 + mt) * 132 + f] = x[(size_t)node * FD + f] + p;
        }
    }
    __syncthreads();

    // Phase 3: support[4 x 128] = xn(rows 0..3) @ weight. Wave w -> Ntile w. Rows 4..15 are zero.
    f32x4 sacc = (f32x4){0.f, 0.f, 0.f, 0.f};
    #pragma unroll
    for (int kk = 0; kk < 4; ++kk) {
        const float* p = &xn[m * 132 + kk * 32 + q * 8];
        bf16x8 a;
        a[0]=(__bf16)p[0]; a[1]=(__bf16)p[1]; a[2]=(__bf16)p[2]; a[3]=(__bf16)p[3];
        a[4]=(__bf16)p[4]; a[5]=(__bf16)p[5]; a[6]=(__bf16)p[6]; a[7]=(__bf16)p[7];
        s16x8 braw = *reinterpret_cast<const s16x8*>(wpack + ((size_t)(kk * 8 + wave) * 64 + lane) * 8);
        sacc = __builtin_amdgcn_mfma_f32_16x16x32_bf16(a, __builtin_bit_cast(bf16x8, braw), sacc, 0, 0, 0);
    }
    if (q == 0) {
        #pragma unroll
        for (int i = 0; i < 4; ++i)
            support[(size_t)(node0 + i) * FD + wave * 16 + m] = f2bf_s(sacc[i]);
    }
}

// out[n][f] = bias[f] + sum_d adj[n*16+d] * support[src[n*16+d]][f]
// Thread handles 4 features: ushort4 (8B) gathers, float4 store.
__global__ __launch_bounds__(256) void final_agg_k(
    const short* __restrict__ support, const float* __restrict__ adj,
    const int* __restrict__ esrc, const float* __restrict__ bias,
    float* __restrict__ out)
{
    int tid = blockIdx.x * 256 + threadIdx.x;      // over 50000*32
    int n  = tid >> 5;
    int f4 = (tid & 31) * 4;
    f32x4 a = *reinterpret_cast<const f32x4*>(bias + f4);
    int eb = n * DEG;
    #pragma unroll
    for (int d = 0; d < DEG; ++d) {
        int s = esrc[eb + d];
        float w = adj[eb + d];
        ushort4 sv = *reinterpret_cast<const ushort4*>(support + (size_t)s * FD + f4);
        a.x += w * bf2f((short)sv.x);
        a.y += w * bf2f((short)sv.y);
        a.z += w * bf2f((short)sv.z);
        a.w += w * bf2f((short)sv.w);
    }
    *reinterpret_cast<f32x4*>(out + (size_t)n * FD + f4) = a;
}

extern "C" void kernel_launch(void* const* d_in, const int* in_sizes, int n_in,
                              void* d_out, int out_size, void* d_ws, size_t ws_size,
                              hipStream_t stream) {
    const float* x      = (const float*)d_in[0];
    const float* weight = (const float*)d_in[1];
    const float* bias   = (const float*)d_in[2];
    const float* wm     = (const float*)d_in[3];
    const float* adj    = (const float*)d_in[4];
    const int*   esrc   = (const int*)d_in[5];
    // d_in[6] edge_dst unused: dst(e) = e/16 by construction.

    // ws: [0,64K) Wm bf16 | [64K,96K) weight bf16 | [96K,+12.8M) x bf16 | [+12.8M,+25.6M) support bf16
    short* bpack   = (short*)d_ws;
    short* wpack   = (short*)((char*)d_ws + 65536);
    short* xbf     = (short*)((char*)d_ws + 98304);
    short* support = (short*)((char*)d_ws + 98304 + (size_t)NNODES * FD * 2);
    float* out     = (float*)d_out;

    pack_k<<<3125, 256, 0, stream>>>(x, wm, weight, bpack, wpack, xbf);
    mask_agg_support_k<<<NNODES / 4, 512, 0, stream>>>(x, xbf, esrc, bpack, wpack, support);
    final_agg_k<<<(NNODES * 32) / 256, 256, 0, stream>>>(support, adj, esrc, bias, out);
}

// Round 4
// 205.000 us; speedup vs baseline: 1.4972x; 1.4972x over previous
//
#include <hip/hip_runtime.h>
#include <stdint.h>
#include <stddef.h>

// gcnmask: N=50000, DEG=16, F=128. Edges grouped by dst (dst = e/16) -> no atomics.
// R4: algebraic collapse. mask = sigmoid([cen|nei]@Wm) = sigmoid(Z[dst] + Y[src]) with
//     Z = x@Wm_top, Y = x@Wm_bot computed ONCE per node (3.2 GF) instead of per edge (52.4 GF).
//     Pipeline: pack -> zy (node GEMM, writes Zbf + XY=(xbf|Ybf) interleaved uints into d_out
//     as scratch) -> edge (sigmoid+agg via full-row coalesced gathers, support GEMM) -> final.

#define NNODES 50000
#define DEG    16
#define FD     128

typedef __bf16 bf16x8 __attribute__((ext_vector_type(8)));
typedef short  s16x8  __attribute__((ext_vector_type(8)));
typedef float  f32x4  __attribute__((ext_vector_type(4)));
typedef float  f32x2  __attribute__((ext_vector_type(2)));

__device__ __forceinline__ short f2bf_s(float f) {
    union { float f; uint32_t u; } v; v.f = f;
    uint32_t r = v.u + 0x7fffu + ((v.u >> 16) & 1u);   // RNE
    return (short)(r >> 16);
}
__device__ __forceinline__ float bf2f(uint32_t lo16) {
    union { uint32_t u; float f; } v; v.u = lo16 << 16;
    return v.f;
}

// Pack Wmb[k=0..127][c=0..255] (c<128: Wm_top col c; c>=128: Wm_bot col c-128) and
// weight[128x128] into bf16 B-fragment order for mfma_f32_16x16x32_bf16:
//   idx = ((kk*NT + ntile)*64 + q*16 + n15)*8 + (k&7), kk = k>>5, q = (k>>3)&3.
__global__ __launch_bounds__(256) void pack_k(const float* __restrict__ wm,
                                              const float* __restrict__ w,
                                              short* __restrict__ wmb,
                                              short* __restrict__ wpack) {
    int tid = blockIdx.x * 256 + threadIdx.x;
    if (tid < 128 * 256) {
        int k = tid >> 8, c = tid & 255;
        float v = (c < 128) ? wm[k * 128 + c] : wm[(128 + k) * 128 + (c - 128)];
        int idx = (((k >> 5) * 16 + (c >> 4)) * 64 + ((k >> 3) & 3) * 16 + (c & 15)) * 8 + (k & 7);
        wmb[idx] = f2bf_s(v);
    }
    if (tid < 128 * 128) {
        int k = tid >> 7, n = tid & 127;
        int idx = (((k >> 5) * 8 + (n >> 4)) * 64 + ((k >> 3) & 3) * 16 + (n & 15)) * 8 + (k & 7);
        wpack[idx] = f2bf_s(w[tid]);
    }
}

// ZY = x @ Wmb  ([50000x128] @ [128x256]). Block = 16 nodes, 4 waves; wave w -> ntiles 4w..4w+3.
// Epilogue: c<128 -> Zbf[row][c]; c>=128 -> XY[row][c-128] = uint(bf16(x[row][f]) | bf16(Y)<<16).
__global__ __launch_bounds__(256) void zy_k(const float* __restrict__ x,
                                            const short* __restrict__ wmb,
                                            short* __restrict__ zbf,
                                            uint32_t* __restrict__ xy) {
    const int tid = threadIdx.x, wave = tid >> 6, lane = tid & 63;
    const int q = lane >> 4, m = lane & 15;
    const int node0 = blockIdx.x * 16;

    f32x4 acc[4];
    #pragma unroll
    for (int nt = 0; nt < 4; ++nt) acc[nt] = (f32x4){0.f, 0.f, 0.f, 0.f};

    #pragma unroll
    for (int kk = 0; kk < 4; ++kk) {
        // A[row=m][k=q*8+j], k_global = kk*32 + q*8
        const float* rp = x + (size_t)(node0 + m) * FD + kk * 32 + q * 8;
        f32x4 lo = *reinterpret_cast<const f32x4*>(rp);
        f32x4 hi = *reinterpret_cast<const f32x4*>(rp + 4);
        bf16x8 a;
        a[0]=(__bf16)lo.x; a[1]=(__bf16)lo.y; a[2]=(__bf16)lo.z; a[3]=(__bf16)lo.w;
        a[4]=(__bf16)hi.x; a[5]=(__bf16)hi.y; a[6]=(__bf16)hi.z; a[7]=(__bf16)hi.w;
        #pragma unroll
        for (int nt = 0; nt < 4; ++nt) {
            int frag = kk * 16 + wave * 4 + nt;
            s16x8 braw = *reinterpret_cast<const s16x8*>(wmb + ((size_t)frag * 64 + lane) * 8);
            acc[nt] = __builtin_amdgcn_mfma_f32_16x16x32_bf16(a, __builtin_bit_cast(bf16x8, braw), acc[nt], 0, 0, 0);
        }
    }
    // C/D: col = m, row = q*4+i
    #pragma unroll
    for (int nt = 0; nt < 4; ++nt) {
        int c = (wave * 4 + nt) * 16 + m;
        #pragma unroll
        for (int i = 0; i < 4; ++i) {
            int row = node0 + q * 4 + i;
            float val = acc[nt][i];
            if (c < 128) {
                zbf[(size_t)row * FD + c] = f2bf_s(val);
            } else {
                int f = c - 128;
                float xv = x[(size_t)row * FD + f];               // L1-hot (A-frags just read these rows)
                uint32_t u = (uint32_t)(uint16_t)f2bf_s(xv) | ((uint32_t)(uint16_t)f2bf_s(val) << 16);
                xy[(size_t)row * FD + f] = u;
            }
        }
    }
}

// Block = 256 thr = 4 waves x 4 nodes. Lane owns features f = 2*lane, 2*lane+1.
// Per node: 16 full-row coalesced gathers of XY (uint2/lane = 512 B/row), mask = sigmoid(Z+Y),
// agg += mask*x_src; x_new -> LDS. Then support[16x128] = x_new @ weight (wave w -> ntiles 2w,2w+1).
__global__ __launch_bounds__(256) void edge_k(const short* __restrict__ zbf,
                                              const uint32_t* __restrict__ xy,
                                              const int* __restrict__ esrc,
                                              const short* __restrict__ wpack,
                                              short* __restrict__ support) {
    __shared__ float xn[16 * 132];   // stride 132: phase-3 b128 reads conflict-light
    const int tid = threadIdx.x, wave = tid >> 6, lane = tid & 63;
    const int q = lane >> 4, m = lane & 15;
    const int node0 = blockIdx.x * 16;

    for (int mt = 0; mt < 4; ++mt) {
        const int n = node0 + wave * 4 + mt;
        int srcv = esrc[n * DEG + (lane & 15)];
        uint32_t z2 = *reinterpret_cast<const uint32_t*>(zbf + (size_t)n * FD + 2 * lane);
        float zc0 = bf2f(z2 & 0xffffu), zc1 = bf2f(z2 >> 16);
        float a0a = 0.f, a0b = 0.f, a1a = 0.f, a1b = 0.f;
        #pragma unroll
        for (int e = 0; e < 16; ++e) {
            int s = __shfl(srcv, e);
            uint2 u = *reinterpret_cast<const uint2*>(xy + (size_t)s * FD + 2 * lane);
            float x0 = bf2f(u.x & 0xffffu), y0 = bf2f(u.x >> 16);
            float x1 = bf2f(u.y & 0xffffu), y1 = bf2f(u.y >> 16);
            float g0 = 1.f / (1.f + __expf(-(zc0 + y0)));
            float g1 = 1.f / (1.f + __expf(-(zc1 + y1)));
            if (e & 1) { a0b += g0 * x0; a1b += g1 * x1; }
            else       { a0a += g0 * x0; a1a += g1 * x1; }
        }
        uint2 c = *reinterpret_cast<const uint2*>(xy + (size_t)n * FD + 2 * lane);
        f32x2 xv;
        xv.x = bf2f(c.x & 0xffffu) + a0a + a0b;
        xv.y = bf2f(c.y & 0xffffu) + a1a + a1b;
        *reinterpret_cast<f32x2*>(&xn[(wave * 4 + mt) * 132 + 2 * lane]) = xv;
    }
    __syncthreads();

    // support = xn[16x128] @ weight; wave w -> ntiles 2w, 2w+1
    f32x4 sacc[2];
    sacc[0] = (f32x4){0.f, 0.f, 0.f, 0.f};
    sacc[1] = (f32x4){0.f, 0.f, 0.f, 0.f};
    #pragma unroll
    for (int kk = 0; kk < 4; ++kk) {
        const float* p = &xn[m * 132 + kk * 32 + q * 8];
        bf16x8 a;
        a[0]=(__bf16)p[0]; a[1]=(__bf16)p[1]; a[2]=(__bf16)p[2]; a[3]=(__bf16)p[3];
        a[4]=(__bf16)p[4]; a[5]=(__bf16)p[5]; a[6]=(__bf16)p[6]; a[7]=(__bf16)p[7];
        #pragma unroll
        for (int t = 0; t < 2; ++t) {
            int nt = wave * 2 + t;
            s16x8 braw = *reinterpret_cast<const s16x8*>(wpack + ((size_t)(kk * 8 + nt) * 64 + lane) * 8);
            sacc[t] = __builtin_amdgcn_mfma_f32_16x16x32_bf16(a, __builtin_bit_cast(bf16x8, braw), sacc[t], 0, 0, 0);
        }
    }
    #pragma unroll
    for (int t = 0; t < 2; ++t) {
        int nt = wave * 2 + t;
        #pragma unroll
        for (int i = 0; i < 4; ++i)
            support[(size_t)(node0 + q * 4 + i) * FD + nt * 16 + m] = f2bf_s(sacc[t][i]);
    }
}

// Wave per node; lane owns f = 2*lane, 2*lane+1. 16 coalesced row-gathers of support (bf16).
__global__ __launch_bounds__(256) void final_k(const short* __restrict__ support,
                                               const float* __restrict__ adj,
                                               const int* __restrict__ esrc,
                                               const float* __restrict__ bias,
                                               float* __restrict__ out) {
    const int tid = threadIdx.x, wave = tid >> 6, lane = tid & 63;
    const int n = blockIdx.x * 4 + wave;
    int srcv = esrc[n * DEG + (lane & 15)];
    float adjv = adj[n * DEG + (lane & 15)];
    f32x2 b = *reinterpret_cast<const f32x2*>(bias + 2 * lane);
    float a0 = b.x, a1 = b.y;
    #pragma unroll
    for (int e = 0; e < 16; ++e) {
        int s = __shfl(srcv, e);
        float w = __shfl(adjv, e);
        uint32_t u = *reinterpret_cast<const uint32_t*>(support + (size_t)s * FD + 2 * lane);
        a0 += w * bf2f(u & 0xffffu);
        a1 += w * bf2f(u >> 16);
    }
    f32x2 r; r.x = a0; r.y = a1;
    *reinterpret_cast<f32x2*>(out + (size_t)n * FD + 2 * lane) = r;
}

extern "C" void kernel_launch(void* const* d_in, const int* in_sizes, int n_in,
                              void* d_out, int out_size, void* d_ws, size_t ws_size,
                              hipStream_t stream) {
    const float* x      = (const float*)d_in[0];
    const float* weight = (const float*)d_in[1];
    const float* bias   = (const float*)d_in[2];
    const float* wm     = (const float*)d_in[3];
    const float* adj    = (const float*)d_in[4];
    const int*   esrc   = (const int*)d_in[5];
    // d_in[6] edge_dst unused: dst(e) = e/16 by construction.

    // ws: [0,64K) Wmb packed | [64K,96K) weight packed | [96K,+12.8M) Zbf | then support bf16.
    // XY (uint per (node,f): low=bf16(x), high=bf16(Y)) lives in d_out (exactly out_size bytes),
    // fully consumed by edge_k before final_k overwrites d_out with the real output.
    short*    wmb     = (short*)d_ws;
    short*    wpack   = (short*)((char*)d_ws + 65536);
    short*    zbf     = (short*)((char*)d_ws + 98304);
    short*    support = (short*)((char*)d_ws + 98304 + (size_t)NNODES * FD * 2);
    uint32_t* xy      = (uint32_t*)d_out;
    float*    out     = (float*)d_out;

    pack_k <<<128,   256, 0, stream>>>(wm, weight, wmb, wpack);
    zy_k   <<<NNODES / 16, 256, 0, stream>>>(x, wmb, zbf, xy);
    edge_k <<<NNODES / 16, 256, 0, stream>>>(zbf, xy, esrc, wpack, support);
    final_k<<<NNODES / 4,  256, 0, stream>>>(support, adj, esrc, bias, out);
}

// Round 5
// 196.792 us; speedup vs baseline: 1.5596x; 1.0417x over previous
//
#include <hip/hip_runtime.h>
#include <stdint.h>
#include <stddef.h>

// gcnmask: N=50000, DEG=16, F=128. Edges grouped by dst (dst = e/16) -> no atomics.
// R5: scalarized gathers. Per-wave-uniform edge lists via readfirstlane -> s_load_dwordx16;
//     gather addr = SGPR base + lane offset (zero VALU addr math). Sigmoid folded to
//     rcp(1+exp2(z'+y')) with Z,Y stored pre-scaled by -log2(e).

#define NNODES 50000
#define DEG    16
#define FD     128

#define NEG_LOG2E -1.44269504f

typedef __bf16 bf16x8 __attribute__((ext_vector_type(8)));
typedef short  s16x8  __attribute__((ext_vector_type(8)));
typedef float  f32x4  __attribute__((ext_vector_type(4)));
typedef float  f32x2  __attribute__((ext_vector_type(2)));

__device__ __forceinline__ short f2bf_s(float f) {
    union { float f; uint32_t u; } v; v.f = f;
    uint32_t r = v.u + 0x7fffu + ((v.u >> 16) & 1u);   // RNE
    return (short)(r >> 16);
}
__device__ __forceinline__ float bflo(uint32_t u) {    // low bf16 -> f32
    union { uint32_t u; float f; } v; v.u = u << 16;
    return v.f;
}
__device__ __forceinline__ float bfhi(uint32_t u) {    // high bf16 -> f32
    union { uint32_t u; float f; } v; v.u = u & 0xffff0000u;
    return v.f;
}

// Pack Wmb[k=0..127][c=0..255] (c<128: Wm_top col c; c>=128: Wm_bot col c-128) and
// weight[128x128] into bf16 B-fragment order for mfma_f32_16x16x32_bf16:
//   idx = ((kk*NT + ntile)*64 + q*16 + n15)*8 + (k&7), kk = k>>5, q = (k>>3)&3.
__global__ __launch_bounds__(256) void pack_k(const float* __restrict__ wm,
                                              const float* __restrict__ w,
                                              short* __restrict__ wmb,
                                              short* __restrict__ wpack) {
    int tid = blockIdx.x * 256 + threadIdx.x;
    if (tid < 128 * 256) {
        int k = tid >> 8, c = tid & 255;
        float v = (c < 128) ? wm[k * 128 + c] : wm[(128 + k) * 128 + (c - 128)];
        int idx = (((k >> 5) * 16 + (c >> 4)) * 64 + ((k >> 3) & 3) * 16 + (c & 15)) * 8 + (k & 7);
        wmb[idx] = f2bf_s(v);
    }
    if (tid < 128 * 128) {
        int k = tid >> 7, n = tid & 127;
        int idx = (((k >> 5) * 8 + (n >> 4)) * 64 + ((k >> 3) & 3) * 16 + (n & 15)) * 8 + (k & 7);
        wpack[idx] = f2bf_s(w[tid]);
    }
}

// ZY = x @ Wmb ([50000x128] @ [128x256]). Block = 16 nodes, 4 waves; wave w -> ntiles 4w..4w+3.
// Epilogue: c<128 -> zbf = bf16(-log2e * Z); c>=128 -> xy[row][c-128] = bf16(x) | bf16(-log2e*Y)<<16.
__global__ __launch_bounds__(256) void zy_k(const float* __restrict__ x,
                                            const short* __restrict__ wmb,
                                            short* __restrict__ zbf,
                                            uint32_t* __restrict__ xy) {
    const int tid = threadIdx.x, wave = tid >> 6, lane = tid & 63;
    const int q = lane >> 4, m = lane & 15;
    const int node0 = blockIdx.x * 16;

    f32x4 acc[4];
    #pragma unroll
    for (int nt = 0; nt < 4; ++nt) acc[nt] = (f32x4){0.f, 0.f, 0.f, 0.f};

    #pragma unroll
    for (int kk = 0; kk < 4; ++kk) {
        const float* rp = x + (size_t)(node0 + m) * FD + kk * 32 + q * 8;
        f32x4 lo = *reinterpret_cast<const f32x4*>(rp);
        f32x4 hi = *reinterpret_cast<const f32x4*>(rp + 4);
        bf16x8 a;
        a[0]=(__bf16)lo.x; a[1]=(__bf16)lo.y; a[2]=(__bf16)lo.z; a[3]=(__bf16)lo.w;
        a[4]=(__bf16)hi.x; a[5]=(__bf16)hi.y; a[6]=(__bf16)hi.z; a[7]=(__bf16)hi.w;
        #pragma unroll
        for (int nt = 0; nt < 4; ++nt) {
            int frag = kk * 16 + wave * 4 + nt;
            s16x8 braw = *reinterpret_cast<const s16x8*>(wmb + ((size_t)frag * 64 + lane) * 8);
            acc[nt] = __builtin_amdgcn_mfma_f32_16x16x32_bf16(a, __builtin_bit_cast(bf16x8, braw), acc[nt], 0, 0, 0);
        }
    }
    // C/D: col = m, row = q*4+i
    #pragma unroll
    for (int nt = 0; nt < 4; ++nt) {
        int c = (wave * 4 + nt) * 16 + m;
        #pragma unroll
        for (int i = 0; i < 4; ++i) {
            int row = node0 + q * 4 + i;
            float val = NEG_LOG2E * acc[nt][i];
            if (c < 128) {
                zbf[(size_t)row * FD + c] = f2bf_s(val);
            } else {
                int f = c - 128;
                float xv = x[(size_t)row * FD + f];               // L1-hot
                uint32_t u = (uint32_t)(uint16_t)f2bf_s(xv) | ((uint32_t)(uint16_t)f2bf_s(val) << 16);
                xy[(size_t)row * FD + f] = u;
            }
        }
    }
}

// Block = 256 thr = 4 waves x 4 nodes each. Lane owns features 2*lane, 2*lane+1.
// Per node: 16 row gathers of XY (uint2/lane, SGPR-base), mask = rcp(1+exp2(z'+y')),
// agg += mask*x; x_new -> LDS. Then support[16x128] = x_new @ weight.
__global__ __launch_bounds__(256) void edge_k(const short* __restrict__ zbf,
                                              const uint32_t* __restrict__ xy,
                                              const int* __restrict__ esrc,
                                              const short* __restrict__ wpack,
                                              short* __restrict__ support) {
    __shared__ float xn[16 * 132];
    const int tid = threadIdx.x, wave = tid >> 6, lane = tid & 63;
    const int q = lane >> 4, m = lane & 15;
    const int node0 = blockIdx.x * 16;

    #pragma unroll
    for (int mt = 0; mt < 4; ++mt) {
        const int nu = __builtin_amdgcn_readfirstlane(node0 + wave * 4 + mt);
        const int* ep = esrc + nu * DEG;               // uniform + const -> s_load_dwordx16
        uint32_t z2 = reinterpret_cast<const uint32_t*>(zbf + (size_t)nu * FD)[lane];
        float zn0 = bflo(z2), zn1 = bfhi(z2);          // pre-scaled by -log2e
        float a0a = 0.f, a0b = 0.f, a1a = 0.f, a1b = 0.f;
        #pragma unroll
        for (int e = 0; e < 16; ++e) {
            int s = ep[e];                             // SGPR
            uint2 u = reinterpret_cast<const uint2*>(xy + (size_t)s * FD)[lane];
            float g0 = __builtin_amdgcn_rcpf(1.f + __builtin_amdgcn_exp2f(zn0 + bfhi(u.x)));
            float g1 = __builtin_amdgcn_rcpf(1.f + __builtin_amdgcn_exp2f(zn1 + bfhi(u.y)));
            if (e & 1) { a0b += g0 * bflo(u.x); a1b += g1 * bflo(u.y); }
            else       { a0a += g0 * bflo(u.x); a1a += g1 * bflo(u.y); }
        }
        uint2 c = reinterpret_cast<const uint2*>(xy + (size_t)nu * FD)[lane];
        f32x2 xv;
        xv.x = bflo(c.x) + a0a + a0b;
        xv.y = bflo(c.y) + a1a + a1b;
        *reinterpret_cast<f32x2*>(&xn[(wave * 4 + mt) * 132 + 2 * lane]) = xv;
    }
    __syncthreads();

    // support = xn[16x128] @ weight; wave w -> ntiles 2w, 2w+1
    f32x4 sacc[2];
    sacc[0] = (f32x4){0.f, 0.f, 0.f, 0.f};
    sacc[1] = (f32x4){0.f, 0.f, 0.f, 0.f};
    #pragma unroll
    for (int kk = 0; kk < 4; ++kk) {
        const float* p = &xn[m * 132 + kk * 32 + q * 8];
        bf16x8 a;
        a[0]=(__bf16)p[0]; a[1]=(__bf16)p[1]; a[2]=(__bf16)p[2]; a[3]=(__bf16)p[3];
        a[4]=(__bf16)p[4]; a[5]=(__bf16)p[5]; a[6]=(__bf16)p[6]; a[7]=(__bf16)p[7];
        #pragma unroll
        for (int t = 0; t < 2; ++t) {
            int nt = wave * 2 + t;
            s16x8 braw = *reinterpret_cast<const s16x8*>(wpack + ((size_t)(kk * 8 + nt) * 64 + lane) * 8);
            sacc[t] = __builtin_amdgcn_mfma_f32_16x16x32_bf16(a, __builtin_bit_cast(bf16x8, braw), sacc[t], 0, 0, 0);
        }
    }
    #pragma unroll
    for (int t = 0; t < 2; ++t) {
        int nt = wave * 2 + t;
        #pragma unroll
        for (int i = 0; i < 4; ++i)
            support[(size_t)(node0 + q * 4 + i) * FD + nt * 16 + m] = f2bf_s(sacc[t][i]);
    }
}

// Wave handles 2 nodes; lane owns features 2*lane, 2*lane+1. Scalarized esrc/adj
// (SGPR), 16 coalesced row gathers of support (bf16 pairs) per node.
__global__ __launch_bounds__(256) void final_k(const short* __restrict__ support,
                                               const float* __restrict__ adj,
                                               const int* __restrict__ esrc,
                                               const float* __restrict__ bias,
                                               float* __restrict__ out) {
    const int tid = threadIdx.x, wave = tid >> 6, lane = tid & 63;
    const int n0 = blockIdx.x * 8 + wave * 2;
    f32x2 b = *reinterpret_cast<const f32x2*>(bias + 2 * lane);
    #pragma unroll
    for (int t = 0; t < 2; ++t) {
        const int nu = __builtin_amdgcn_readfirstlane(n0 + t);
        const int* ep = esrc + nu * DEG;               // uniform -> s_load
        const float* ap = adj + nu * DEG;              // uniform -> s_load
        float a0 = b.x, a1 = b.y, c0 = 0.f, c1 = 0.f;
        #pragma unroll
        for (int e = 0; e < 16; ++e) {
            int s = ep[e];
            float w = ap[e];                           // SGPR operand in v_fma
            uint32_t u = reinterpret_cast<const uint32_t*>(support + (size_t)s * FD)[lane];
            if (e & 1) { c0 += w * bflo(u); c1 += w * bfhi(u); }
            else       { a0 += w * bflo(u); a1 += w * bfhi(u); }
        }
        f32x2 r; r.x = a0 + c0; r.y = a1 + c1;
        *reinterpret_cast<f32x2*>(out + (size_t)nu * FD + 2 * lane) = r;
    }
}

extern "C" void kernel_launch(void* const* d_in, const int* in_sizes, int n_in,
                              void* d_out, int out_size, void* d_ws, size_t ws_size,
                              hipStream_t stream) {
    const float* x      = (const float*)d_in[0];
    const float* weight = (const float*)d_in[1];
    const float* bias   = (const float*)d_in[2];
    const float* wm     = (const float*)d_in[3];
    const float* adj    = (const float*)d_in[4];
    const int*   esrc   = (const int*)d_in[5];
    // d_in[6] edge_dst unused: dst(e) = e/16 by construction.

    // ws: [0,64K) Wmb packed | [64K,96K) weight packed | [96K,+12.8M) Zbf | then support bf16.
    // XY (uint per (node,f): low=bf16(x), high=bf16(-log2e*Y)) lives in d_out, fully consumed
    // by edge_k before final_k overwrites d_out with the real output.
    short*    wmb     = (short*)d_ws;
    short*    wpack   = (short*)((char*)d_ws + 65536);
    short*    zbf     = (short*)((char*)d_ws + 98304);
    short*    support = (short*)((char*)d_ws + 98304 + (size_t)NNODES * FD * 2);
    uint32_t* xy      = (uint32_t*)d_out;
    float*    out     = (float*)d_out;

    pack_k <<<128,         256, 0, stream>>>(wm, weight, wmb, wpack);
    zy_k   <<<NNODES / 16, 256, 0, stream>>>(x, wmb, zbf, xy);
    edge_k <<<NNODES / 16, 256, 0, stream>>>(zbf, xy, esrc, wpack, support);
    final_k<<<NNODES / 8,  256, 0, stream>>>(support, adj, esrc, bias, out);
}